// Round 6
// baseline (102.618 us; speedup 1.0000x reference)
//
#include <hip/hip_runtime.h>

#define NPTS 1024
#define D 64
#define LOG2E 1.44269504088896f
#define LN2C  0.69314718055995f

typedef float f2 __attribute__((ext_vector_type(2)));

__device__ __forceinline__ float rcp_fast(float x)  { return __builtin_amdgcn_rcpf(x); }
__device__ __forceinline__ float exp2_fast(float x) { return __builtin_amdgcn_exp2f(x); }
__device__ __forceinline__ float sqrt_fast(float x) { return __builtin_amdgcn_sqrtf(x); }

// Kernel A: hib = x@W1_i + b1 (UNscaled), hj = x@W1_j (UNscaled),
//           wib = (x@Wc_i + bc)*log2e, wj = (x@Wc_j)*log2e  (gate path keeps exp2)
//           hjsum[c] += sum over this block's 4 rows of hj (atomic)
__global__ __launch_bounds__(256) void precomp_kernel(
    const float* __restrict__ x, const float* __restrict__ W1,
    const float* __restrict__ b1, const float* __restrict__ Wc,
    const float* __restrict__ bc,
    float* __restrict__ hib, float* __restrict__ hj,
    float* __restrict__ wib, float* __restrict__ wj,
    float* __restrict__ hjsum)
{
    __shared__ float xs[4][D];
    __shared__ float hjp[4][D];
    const int t = threadIdx.x;
    const int r = t >> 6, c = t & 63;
    const int row = blockIdx.x * 4 + r;
    xs[r][c] = x[row * D + c];
    __syncthreads();
    float ai = 0.f, aj = 0.f;
    #pragma unroll 8
    for (int k = 0; k < D; ++k) {
        const float xv = xs[r][k];
        ai = fmaf(xv, W1[k * D + c], ai);          // W1_i column c
        aj = fmaf(xv, W1[(D + k) * D + c], aj);    // W1_j column c
    }
    hib[row * D + c] = ai + b1[c];
    hj[row * D + c]  = aj;
    hjp[r][c] = aj;
    // Wc dots: wave reduction over the 64 channels
    float pi = xs[r][c] * Wc[c];
    float pj = xs[r][c] * Wc[D + c];
    #pragma unroll
    for (int off = 32; off; off >>= 1) {
        pi += __shfl_down(pi, off, 64);
        pj += __shfl_down(pj, off, 64);
    }
    if (c == 0) { wib[row] = (pi + bc[0]) * LOG2E; wj[row] = pj * LOG2E; }
    __syncthreads();
    if (t < 64) atomicAdd(&hjsum[t], hjp[0][t] + hjp[1][t] + hjp[2][t] + hjp[3][t]);
}

// Kernel B: 4 rows per block, 512 threads (8 waves).
// Sum_j silu(h) = 0.5*Sum_j h (closed form) + Sum_j g(h^2),
// g(u) = (26.25u + 0.625u^2)/(105 + 11.25u + 0.0625u^2)  [tanh Pade, even part;
// err <1e-4 for |h|<3, <2e-3 for |h|<4 — absmax budget 0.137]
__global__ __launch_bounds__(512) void pair_kernel(
    const float* __restrict__ coords,
    const float* __restrict__ W1, const float* __restrict__ W2,
    const float* __restrict__ b2, const float* __restrict__ Wc,
    const float* __restrict__ hib_g, const float* __restrict__ hj_g,
    const float* __restrict__ wib_g, const float* __restrict__ wj_g,
    const float* __restrict__ hjsum,
    float* __restrict__ out)
{
    __shared__ float cs[NPTS * 3];      // 12 KB coords
    __shared__ float wjs[NPTS];         // 4 KB (log2e-scaled)
    __shared__ float dist2[NPTS][4];    // 16 KB dists, [j][row]
    __shared__ float S4[8][4][D];       // 8 KB per-wave partial Sum g
    __shared__ float S2[4][D];          // assembled S
    __shared__ float dred[8][4][4];     // per-wave {dx,dy,dz,dsum}

    const int t = threadIdx.x;
    const int i0 = blockIdx.x * 4;

    for (int k = t; k < NPTS * 3; k += 512) cs[k] = coords[k];
    for (int k = t; k < NPTS; k += 512) wjs[k] = wj_g[k];
    __syncthreads();

    const float wcd = Wc[2 * D] * LOG2E;
    float dcx[4] = {0,0,0,0}, dcy[4] = {0,0,0,0}, dcz[4] = {0,0,0,0}, dsm[4] = {0,0,0,0};

    // ---- Phase 1: dists (+row sums) + silu-gated coordinate update (exp2 path)
    #pragma unroll
    for (int is = 0; is < 4; ++is) {
        const int i = i0 + is;
        const float cix = cs[i*3+0], ciy = cs[i*3+1], ciz = cs[i*3+2];
        const float wib = wib_g[i];
        #pragma unroll
        for (int it = 0; it < 2; ++it) {
            const int j = it * 512 + t;
            const float rx = cix - cs[j*3+0];
            const float ry = ciy - cs[j*3+1];
            const float rz = ciz - cs[j*3+2];
            const float d = sqrt_fast(fmaf(rx, rx, fmaf(ry, ry, rz * rz)));
            dist2[j][is] = d;
            dsm[is] += d;
            const float tv = fmaf(d, wcd, wib + wjs[j]);
            const float e  = exp2_fast(-tv);
            const float sw = tv * rcp_fast(1.0f + e);       // log2e*silu(w)
            dcx[is] = fmaf(sw, rx, dcx[is]);
            dcy[is] = fmaf(sw, ry, dcy[is]);
            dcz[is] = fmaf(sw, rz, dcz[is]);
        }
    }
    {
        const int w = t >> 6, l = t & 63;
        #pragma unroll
        for (int is = 0; is < 4; ++is) {
            float vx = dcx[is], vy = dcy[is], vz = dcz[is], vd = dsm[is];
            #pragma unroll
            for (int off = 32; off; off >>= 1) {
                vx += __shfl_down(vx, off, 64);
                vy += __shfl_down(vy, off, 64);
                vz += __shfl_down(vz, off, 64);
                vd += __shfl_down(vd, off, 64);
            }
            if (l == 0) {
                dred[w][is][0] = vx; dred[w][is][1] = vy;
                dred[w][is][2] = vz; dred[w][is][3] = vd;
            }
        }
    }
    __syncthreads();   // dist2 ready

    // ---- Phase 2: wave w owns j in [w*128, w*128+128); 16 lanes x 4 j-subslots.
    // Each thread: 4 rows x 4 channels (2 f2 pairs), packed-fp32 Pade chains.
    const int w = t >> 6, l = t & 63;
    const int sub = l >> 4;          // j sub-slot 0..3
    const int q   = l & 15;          // channel quad
    f2 hibp[4][2], w1dp[2];
    #pragma unroll
    for (int ir = 0; ir < 4; ++ir) {
        hibp[ir][0] = *(const f2*)&hib_g[(i0 + ir) * D + q * 4];
        hibp[ir][1] = *(const f2*)&hib_g[(i0 + ir) * D + q * 4 + 2];
    }
    w1dp[0] = *(const f2*)&W1[2 * D * D + q * 4];
    w1dp[1] = *(const f2*)&W1[2 * D * D + q * 4 + 2];
    f2 acc[4][2];
    #pragma unroll
    for (int ir = 0; ir < 4; ++ir) { acc[ir][0] = (f2)0.f; acc[ir][1] = (f2)0.f; }

    const int jbase = w * 128 + sub;
    const float* __restrict__ hjp2 = hj_g + (size_t)jbase * D + q * 4;
    #pragma unroll 4
    for (int it = 0; it < 32; ++it) {
        const int j = jbase + it * 4;
        const float4 hv4 = *(const float4*)(hjp2 + (size_t)it * 4 * D);  // dwordx4
        f2 hvp[2]; hvp[0].x = hv4.x; hvp[0].y = hv4.y; hvp[1].x = hv4.z; hvp[1].y = hv4.w;
        const float4 dd = *(const float4*)&dist2[j][0];                  // ds_read_b128
        const float dr[4] = {dd.x, dd.y, dd.z, dd.w};
        #pragma unroll
        for (int ir = 0; ir < 4; ++ir) {
            f2 dv; dv.x = dr[ir]; dv.y = dr[ir];
            #pragma unroll
            for (int p = 0; p < 2; ++p) {
                const f2 tv  = dv * w1dp[p] + hibp[ir][p] + hvp[p];
                const f2 u   = tv * tv;
                const f2 num = (u * 0.625f + 26.25f) * u;
                const f2 den = (u * 0.0625f + 11.25f) * u + 105.0f;
                f2 r; r.x = rcp_fast(den.x); r.y = rcp_fast(den.y);
                acc[ir][p] += num * r;
            }
        }
    }
    // reduce the 4 j-subslot partials (lanes differing in bits 4..5, same q)
    #pragma unroll
    for (int ir = 0; ir < 4; ++ir) {
        #pragma unroll
        for (int p = 0; p < 2; ++p) {
            float a0 = acc[ir][p].x, a1 = acc[ir][p].y;
            #pragma unroll
            for (int off = 16; off <= 32; off <<= 1) {
                a0 += __shfl_xor(a0, off, 64);
                a1 += __shfl_xor(a1, off, 64);
            }
            if (sub == 0) {
                S4[w][ir][q * 4 + p * 2]     = a0;
                S4[w][ir][q * 4 + p * 2 + 1] = a1;
            }
        }
    }
    __syncthreads();

    // ---- Phase 3a: assemble S = Sum g  +  0.5*Sum h (closed form)
    if (t < 256) {
        const int is = t >> 6, cc = t & 63;
        float s = 0.f;
        #pragma unroll
        for (int ww = 0; ww < 8; ++ww) s += S4[ww][is][cc];
        float dsum = 0.f;
        #pragma unroll
        for (int ww = 0; ww < 8; ++ww) dsum += dred[ww][is][3];
        s += 0.5f * (fmaf(1024.f, hib_g[(i0 + is) * D + cc],
                          fmaf(dsum, W1[2 * D * D + cc], hjsum[cc])));
        S2[is][cc] = s;
    }
    __syncthreads();

    // ---- Phase 3b: msg_x[i] = (S/N) @ W2 + b2 ; coords output
    if (t < 256) {
        const int is = t >> 6, cp = t & 63;
        float accv = 0.f;
        #pragma unroll 16
        for (int cc = 0; cc < D; ++cc)
            accv = fmaf(S2[is][cc], W2[cc * D + cp], accv);
        out[(i0 + is) * D + cp] = fmaf(accv, 1.0f / 1024.0f, b2[cp]);
    }
    // coords: 12 outputs (4 rows x 3 comps)
    if (t < 12) {
        const int is = t / 3, comp = t - is * 3;
        float tot = 0.f;
        #pragma unroll
        for (int ww = 0; ww < 8; ++ww) tot += dred[ww][is][comp];
        out[NPTS * D + (i0 + is) * 3 + comp] =
            cs[(i0 + is) * 3 + comp] + tot * (LN2C / 1024.0f);
    }
}

extern "C" void kernel_launch(void* const* d_in, const int* in_sizes, int n_in,
                              void* d_out, int out_size, void* d_ws, size_t ws_size,
                              hipStream_t stream)
{
    const float* x      = (const float*)d_in[0];
    const float* coords = (const float*)d_in[1];
    const float* W1     = (const float*)d_in[2];
    const float* b1     = (const float*)d_in[3];
    const float* W2     = (const float*)d_in[4];
    const float* b2     = (const float*)d_in[5];
    const float* Wc     = (const float*)d_in[6];
    const float* bc     = (const float*)d_in[7];
    float* out = (float*)d_out;

    float* hib   = (float*)d_ws;        // 1024*64
    float* hj    = hib + NPTS * D;      // 1024*64
    float* wib   = hj + NPTS * D;       // 1024
    float* wj    = wib + NPTS;          // 1024
    float* hjsum = wj + NPTS;           // 64

    hipMemsetAsync(hjsum, 0, D * sizeof(float), stream);
    precomp_kernel<<<NPTS / 4, 256, 0, stream>>>(x, W1, b1, Wc, bc,
                                                 hib, hj, wib, wj, hjsum);
    pair_kernel<<<NPTS / 4, 512, 0, stream>>>(coords, W1, W2, b2, Wc,
                                              hib, hj, wib, wj, hjsum, out);
}

// Round 7
// 91.388 us; speedup vs baseline: 1.1229x; 1.1229x over previous
//
#include <hip/hip_runtime.h>

#define NPTS 1024
#define D 64
#define LOG2E 1.44269504088896f
#define LN2C  0.69314718055995f

__device__ __forceinline__ float rcp_fast(float x)  { return __builtin_amdgcn_rcpf(x); }
__device__ __forceinline__ float exp2_fast(float x) { return __builtin_amdgcn_exp2f(x); }
__device__ __forceinline__ float sqrt_fast(float x) { return __builtin_amdgcn_sqrtf(x); }

// Kernel A: hib = (x@W1_i + b1)*log2e, hj = (x@W1_j)*log2e,
//           wib = (x@Wc_i + bc)*log2e, wj = (x@Wc_j)*log2e
__global__ __launch_bounds__(256) void precomp_kernel(
    const float* __restrict__ x, const float* __restrict__ W1,
    const float* __restrict__ b1, const float* __restrict__ Wc,
    const float* __restrict__ bc,
    float* __restrict__ hib, float* __restrict__ hj,
    float* __restrict__ wib, float* __restrict__ wj)
{
    __shared__ float xs[4][D];
    const int t = threadIdx.x;
    const int r = t >> 6, c = t & 63;
    const int row = blockIdx.x * 4 + r;
    xs[r][c] = x[row * D + c];
    __syncthreads();
    float ai = 0.f, aj = 0.f;
    #pragma unroll 8
    for (int k = 0; k < D; ++k) {
        const float xv = xs[r][k];
        ai = fmaf(xv, W1[k * D + c], ai);          // W1_i column c
        aj = fmaf(xv, W1[(D + k) * D + c], aj);    // W1_j column c
    }
    hib[row * D + c] = (ai + b1[c]) * LOG2E;
    hj[row * D + c]  = aj * LOG2E;
    float pi = xs[r][c] * Wc[c];
    float pj = xs[r][c] * Wc[D + c];
    #pragma unroll
    for (int off = 32; off; off >>= 1) {
        pi += __shfl_down(pi, off, 64);
        pj += __shfl_down(pj, off, 64);
    }
    if (c == 0) { wib[row] = (pi + bc[0]) * LOG2E; wj[row] = pj * LOG2E; }
}

// Kernel B: 2 rows per block, 512 threads (8 waves), 512 blocks -> 2 blocks/CU
// = 16 waves/CU = 4 waves/SIMD (vs 2 in round 3) for trans/VALU cross-wave
// overlap. Each wave owns j in [w*128, (w+1)*128) for BOTH phase 1 (dist
// production) and phase 2 (silu sum) -> dist_s is wave-private, no barrier
// between phases.
__global__ __launch_bounds__(512, 4) void pair_kernel(
    const float* __restrict__ coords,
    const float* __restrict__ W1, const float* __restrict__ W2,
    const float* __restrict__ b2, const float* __restrict__ Wc,
    const float* __restrict__ hib_g, const float* __restrict__ hj_g,
    const float* __restrict__ wib_g, const float* __restrict__ wj_g,
    float* __restrict__ out)
{
    __shared__ float cs[NPTS * 3];      // 12 KB coords
    __shared__ float wjs[NPTS];         // 4 KB (log2e-scaled)
    __shared__ float dist_s[2][NPTS];   // 8 KB, wave-private slices
    __shared__ float S4[8][2][D];       // 4 KB per-wave partial S
    __shared__ float S2[2][D];          // assembled S
    __shared__ float dred[8][2][3];     // per-wave coord partials

    const int t = threadIdx.x;
    const int i0 = blockIdx.x * 2;
    const int w = t >> 6, l = t & 63;

    for (int k = t; k < NPTS * 3; k += 512) cs[k] = coords[k];
    for (int k = t; k < NPTS; k += 512) wjs[k] = wj_g[k];
    __syncthreads();

    const float wcd = Wc[2 * D] * LOG2E;
    float dcx[2] = {0.f, 0.f}, dcy[2] = {0.f, 0.f}, dcz[2] = {0.f, 0.f};

    // ---- Phase 1 (wave-private j-range): dist + silu-gated coordinate update
    #pragma unroll
    for (int is = 0; is < 2; ++is) {
        const int i = i0 + is;
        const float cix = cs[i*3+0], ciy = cs[i*3+1], ciz = cs[i*3+2];
        const float wib = wib_g[i];
        #pragma unroll
        for (int it = 0; it < 2; ++it) {
            const int j = w * 128 + it * 64 + l;
            const float rx = cix - cs[j*3+0];
            const float ry = ciy - cs[j*3+1];
            const float rz = ciz - cs[j*3+2];
            const float d = sqrt_fast(fmaf(rx, rx, fmaf(ry, ry, rz * rz)));
            dist_s[is][j] = d;
            const float tv = fmaf(d, wcd, wib + wjs[j]);
            const float e  = exp2_fast(-tv);
            const float sw = tv * rcp_fast(1.0f + e);       // log2e*silu(w)
            dcx[is] = fmaf(sw, rx, dcx[is]);
            dcy[is] = fmaf(sw, ry, dcy[is]);
            dcz[is] = fmaf(sw, rz, dcz[is]);
        }
    }
    // wave-reduce coordinate partials
    #pragma unroll
    for (int is = 0; is < 2; ++is) {
        float vx = dcx[is], vy = dcy[is], vz = dcz[is];
        #pragma unroll
        for (int off = 32; off; off >>= 1) {
            vx += __shfl_down(vx, off, 64);
            vy += __shfl_down(vy, off, 64);
            vz += __shfl_down(vz, off, 64);
        }
        if (l == 0) { dred[w][is][0] = vx; dred[w][is][1] = vy; dred[w][is][2] = vz; }
    }
    // No __syncthreads: dist_s[.][w*128 .. w*128+127] produced and consumed
    // by the SAME wave (LDS ops within a wave execute in program order).

    // ---- Phase 2: wave w owns j in [w*128, w*128+128); 16 lanes x 4 j-subslots
    const int sub = l >> 4;          // j sub-slot 0..3
    const int q   = l & 15;          // channel quad
    const float4 hib0 = *(const float4*)&hib_g[ i0      * D + q * 4];
    const float4 hib1 = *(const float4*)&hib_g[(i0 + 1) * D + q * 4];
    float4 w1d4 = *(const float4*)&W1[2 * D * D + q * 4];
    w1d4.x *= LOG2E; w1d4.y *= LOG2E; w1d4.z *= LOG2E; w1d4.w *= LOG2E;
    float4 acc0 = {0.f, 0.f, 0.f, 0.f};
    float4 acc1 = {0.f, 0.f, 0.f, 0.f};
    const int jbase = w * 128 + sub;
    const float* __restrict__ hjp = hj_g + (size_t)jbase * D + q * 4;

    #define SILU_ACC(accv, tv)                                               \
        { const float e_ = exp2_fast(-(tv));                                 \
          accv = fmaf((tv), rcp_fast(1.0f + e_), accv); }

    #pragma unroll 4
    for (int it = 0; it < 32; ++it) {
        const int j = jbase + it * 4;
        const float4 hv = *(const float4*)(hjp + (size_t)it * 4 * D);  // dwordx4
        const float d0 = dist_s[0][j];
        const float d1 = dist_s[1][j];
        const float t0x = fmaf(d0, w1d4.x, hib0.x) + hv.x;
        const float t0y = fmaf(d0, w1d4.y, hib0.y) + hv.y;
        const float t0z = fmaf(d0, w1d4.z, hib0.z) + hv.z;
        const float t0w = fmaf(d0, w1d4.w, hib0.w) + hv.w;
        const float t1x = fmaf(d1, w1d4.x, hib1.x) + hv.x;
        const float t1y = fmaf(d1, w1d4.y, hib1.y) + hv.y;
        const float t1z = fmaf(d1, w1d4.z, hib1.z) + hv.z;
        const float t1w = fmaf(d1, w1d4.w, hib1.w) + hv.w;
        SILU_ACC(acc0.x, t0x); SILU_ACC(acc0.y, t0y);
        SILU_ACC(acc0.z, t0z); SILU_ACC(acc0.w, t0w);
        SILU_ACC(acc1.x, t1x); SILU_ACC(acc1.y, t1y);
        SILU_ACC(acc1.z, t1z); SILU_ACC(acc1.w, t1w);
    }
    // reduce the 4 j-subslot partials (lanes differing in bits 4..5, same q)
    #pragma unroll
    for (int off = 16; off <= 32; off <<= 1) {
        acc0.x += __shfl_xor(acc0.x, off, 64);
        acc0.y += __shfl_xor(acc0.y, off, 64);
        acc0.z += __shfl_xor(acc0.z, off, 64);
        acc0.w += __shfl_xor(acc0.w, off, 64);
        acc1.x += __shfl_xor(acc1.x, off, 64);
        acc1.y += __shfl_xor(acc1.y, off, 64);
        acc1.z += __shfl_xor(acc1.z, off, 64);
        acc1.w += __shfl_xor(acc1.w, off, 64);
    }
    if (sub == 0) {
        *(float4*)&S4[w][0][q * 4] = acc0;
        *(float4*)&S4[w][1][q * 4] = acc1;
    }
    __syncthreads();

    // ---- Phase 3a: reduce S4 across the 8 waves
    if (t < 128) {
        const int is = t >> 6, cc = t & 63;
        float s = 0.f;
        #pragma unroll
        for (int ww = 0; ww < 8; ++ww) s += S4[ww][is][cc];
        S2[is][cc] = s;
    }
    __syncthreads();

    // ---- Phase 3b: msg_x[i] = (S*ln2/N) @ W2 + b2 ; coords output
    if (t < 128) {
        const int is = t >> 6, cp = t & 63;
        float acc = 0.f;
        #pragma unroll 16
        for (int cc = 0; cc < D; ++cc)
            acc = fmaf(S2[is][cc], W2[cc * D + cp], acc);
        out[(i0 + is) * D + cp] = fmaf(acc, LN2C / 1024.0f, b2[cp]);
    }
    if (t < 6) {
        const int is = t / 3, comp = t - is * 3;
        float tot = 0.f;
        #pragma unroll
        for (int ww = 0; ww < 8; ++ww) tot += dred[ww][is][comp];
        out[NPTS * D + (i0 + is) * 3 + comp] =
            cs[(i0 + is) * 3 + comp] + tot * (LN2C / 1024.0f);
    }
}

extern "C" void kernel_launch(void* const* d_in, const int* in_sizes, int n_in,
                              void* d_out, int out_size, void* d_ws, size_t ws_size,
                              hipStream_t stream)
{
    const float* x      = (const float*)d_in[0];
    const float* coords = (const float*)d_in[1];
    const float* W1     = (const float*)d_in[2];
    const float* b1     = (const float*)d_in[3];
    const float* W2     = (const float*)d_in[4];
    const float* b2     = (const float*)d_in[5];
    const float* Wc     = (const float*)d_in[6];
    const float* bc     = (const float*)d_in[7];
    float* out = (float*)d_out;

    float* hib = (float*)d_ws;        // 1024*64
    float* hj  = hib + NPTS * D;      // 1024*64
    float* wib = hj + NPTS * D;       // 1024
    float* wj  = wib + NPTS;          // 1024

    precomp_kernel<<<NPTS / 4, 256, 0, stream>>>(x, W1, b1, Wc, bc, hib, hj, wib, wj);
    pair_kernel<<<NPTS / 2, 512, 0, stream>>>(coords, W1, W2, b2, Wc,
                                              hib, hj, wib, wj, out);
}